// Round 7
// baseline (254.515 us; speedup 1.0000x reference)
//
#include <hip/hip_runtime.h>
#include <hip/hip_bf16.h>

// SelfAttention fused pipeline, bf16 MFMA path, K-split flash attention.
// x[4,512,48,48] -> GN(32) -> qkv 1x1 conv -> 8-head attn (N=2304,D=64) -> out proj.
//
// ws layout (66.66 MB):
//   po0  [4][2304][512] f32 @ 0          (first 9.44 MB doubles as xnT before attn)
//   po1  [4][2304][512] f32 @ 18874368
//   vp   [4][512][2304] bf16 @ 37748736  (d-major, n-PERMUTED per 64-tile; innerT after attn)
//   qT   [4][8][2304][64] bf16 @ 47185920 (QSCALE folded via W_q staging)
//   kT   [4][8][2304][64] bf16 @ 56623104
//   pl   [2][4][8][2304] f32 @ 66060288
//   stats[4][32] float2     @ 66650112

typedef unsigned short u16;
typedef unsigned int u32;
typedef __attribute__((ext_vector_type(8))) short bf16x8;
typedef __attribute__((ext_vector_type(4))) float f32x4;
typedef __attribute__((ext_vector_type(8))) unsigned short us8;
typedef __attribute__((ext_vector_type(4))) unsigned short us4;

#define B_ 4
#define C_ 512
#define N_ 2304
#define H_ 8
#define D_ 64
#define G_ 32
#define SPLIT 2
#define NT (N_ / 64 / SPLIT)   // 18 k-tiles per split block

// log2(e)/8: folded into W_q at staging so QK^T lands in exp2 domain.
#define QSCALE 0.1803368801111204f
// No max subtraction: exp2-domain scores |s| <~ 12, exp2(s) <= ~4096 fits
// f32/bf16 comfortably; softmax is shift-invariant.

__device__ __forceinline__ u16 f2bf(float f) {
  unsigned u = __float_as_uint(f);
  u += 0x7FFFu + ((u >> 16) & 1u);   // RNE
  return (u16)(u >> 16);
}

__device__ __forceinline__ u32 pack2bf(float lo, float hi) {
  __hip_bfloat162 t = __float22bfloat162_rn(float2{lo, hi});
  u32 r;
  __builtin_memcpy(&r, &t, 4);
  return r;
}

// ---------------- groupnorm stats: one block per (b,g) ----------------
__global__ __launch_bounds__(256) void gn_stats(const float* __restrict__ x,
                                                float2* __restrict__ stats) {
  const int bg = blockIdx.x;
  const float* p = x + (size_t)bg * 16 * N_;
  float s = 0.f, s2 = 0.f;
  for (int i = threadIdx.x; i < 16 * N_ / 4; i += 256) {
    const float4 v = ((const float4*)p)[i];
    s  += v.x + v.y + v.z + v.w;
    s2 += v.x * v.x + v.y * v.y + v.z * v.z + v.w * v.w;
  }
  #pragma unroll
  for (int off = 32; off; off >>= 1) { s += __shfl_down(s, off); s2 += __shfl_down(s2, off); }
  __shared__ float red[8];
  if ((threadIdx.x & 63) == 0) { red[(threadIdx.x >> 6) * 2] = s; red[(threadIdx.x >> 6) * 2 + 1] = s2; }
  __syncthreads();
  if (threadIdx.x == 0) {
    float S = 0.f, S2 = 0.f;
    for (int w = 0; w < 4; w++) { S += red[w * 2]; S2 += red[w * 2 + 1]; }
    const float inv = 1.f / (16.f * N_);
    const float mean = S * inv;
    const float var = S2 * inv - mean * mean;
    stats[bg] = make_float2(mean, rsqrtf(var + 1e-5f));
  }
}

// ---------------- GN apply + transpose -> xnT[b][n][c] bf16 ----------------
__global__ __launch_bounds__(256) void gn_apply_t(
    const float* __restrict__ x, const float2* __restrict__ stats,
    const float* __restrict__ gamma, const float* __restrict__ beta,
    u16* __restrict__ xnT) {
  __shared__ u16 T[64][72];
  const int c0 = blockIdx.x * 64, n0 = blockIdx.y * 64, b = blockIdx.z;
  const int r = threadIdx.x >> 2, ch = (threadIdx.x & 3) * 16;
  const int cc = c0 + r;
  const float2 st = stats[b * G_ + (cc >> 4)];
  const float sc = st.y * gamma[cc];
  const float sh = beta[cc] - st.x * sc;
  const float* src = x + (size_t)(b * C_ + cc) * N_ + n0 + ch;
  #pragma unroll
  for (int j = 0; j < 16; j += 4) {
    const float4 v = *(const float4*)(src + j);
    us4 o; o[0] = f2bf(v.x * sc + sh); o[1] = f2bf(v.y * sc + sh);
    o[2] = f2bf(v.z * sc + sh); o[3] = f2bf(v.w * sc + sh);
    *(us4*)&T[r][ch + j] = o;
  }
  __syncthreads();
  us8 o1, o2;
  #pragma unroll
  for (int j = 0; j < 8; j++) { o1[j] = T[ch + j][r]; o2[j] = T[ch + 8 + j][r]; }
  u16* dst = xnT + (size_t)(b * N_ + n0 + r) * C_ + c0 + ch;
  *(us8*)dst = o1;
  *(us8*)(dst + 8) = o2;
}

// ---------------- GEMM: C[bz][m][n] = A[m][k] * B[bz][n][k]^T ----------------
// A: f32 weights [M][K], cast to bf16 during LDS staging (MODE2 q-rows scaled).
// B: bf16 [bz][N][K] (K contiguous) for both modes.
// MODE 2 (qkv): epilogue scatters q->qT, k->kT ([b][h][n][d]), v->vout
//   (d-major, n-PERMUTED within each 64-col tile so attn PV b-frag is one b128).
// MODE 1 (out proj): f32 output + bias.
template <int MODE>
__global__ __launch_bounds__(256) void gemm_bf16(
    const float* __restrict__ Af, const u16* __restrict__ Bb16,
    void* __restrict__ C, const float* __restrict__ bias,
    u16* __restrict__ qT, u16* __restrict__ kT, u16* __restrict__ vout,
    const int M, const int N, const int K) {
  __shared__ u16 As[128][40];
  __shared__ u16 Bs[128][40];
  const int tid = threadIdx.x;
  const int wave = tid >> 6, lane = tid & 63;
  const int l16 = lane & 15, lq = lane >> 4;
  const int m0 = blockIdx.x * 128, n0 = blockIdx.y * 128, bz = blockIdx.z;
  const int wm = (wave >> 1) * 64, wn = (wave & 1) * 64;
  const u16* Bb = Bb16 + (size_t)bz * N * K;

  f32x4 acc[4][4];
  #pragma unroll
  for (int mi = 0; mi < 4; mi++)
    #pragma unroll
    for (int ni = 0; ni < 4; ni++) {
      acc[mi][ni][0] = 0.f; acc[mi][ni][1] = 0.f; acc[mi][ni][2] = 0.f; acc[mi][ni][3] = 0.f;
    }

  const int r = tid >> 2, c = (tid & 3) * 8;
  for (int kt = 0; kt < K; kt += 32) {
    __syncthreads();
    // A staging: f32 -> bf16 cast (+QSCALE fold for q rows in MODE2)
    #pragma unroll
    for (int half = 0; half < 2; half++) {
      const int row = m0 + r + half * 64;
      const float* ap = Af + (size_t)row * K + kt + c;
      const float4 f0 = *(const float4*)ap;
      const float4 f1 = *(const float4*)(ap + 4);
      const float sc = (MODE == 2 && row < 512) ? QSCALE : 1.0f;
      us8 o;
      o[0] = f2bf(f0.x * sc); o[1] = f2bf(f0.y * sc);
      o[2] = f2bf(f0.z * sc); o[3] = f2bf(f0.w * sc);
      o[4] = f2bf(f1.x * sc); o[5] = f2bf(f1.y * sc);
      o[6] = f2bf(f1.z * sc); o[7] = f2bf(f1.w * sc);
      *(us8*)&As[r + half * 64][c] = o;
    }
    *(us8*)&Bs[r][c]      = *(const us8*)&Bb[(size_t)(n0 + r) * K + kt + c];
    *(us8*)&Bs[r + 64][c] = *(const us8*)&Bb[(size_t)(n0 + r + 64) * K + kt + c];
    __syncthreads();
    bf16x8 af[4], bfr[4];
    #pragma unroll
    for (int mi = 0; mi < 4; mi++) af[mi] = *(const bf16x8*)&As[wm + mi * 16 + l16][lq * 8];
    #pragma unroll
    for (int ni = 0; ni < 4; ni++) bfr[ni] = *(const bf16x8*)&Bs[wn + ni * 16 + l16][lq * 8];
    #pragma unroll
    for (int mi = 0; mi < 4; mi++)
      #pragma unroll
      for (int ni = 0; ni < 4; ni++)
        acc[mi][ni] = __builtin_amdgcn_mfma_f32_16x16x32_bf16(af[mi], bfr[ni], acc[mi][ni], 0, 0, 0);
  }
  #pragma unroll
  for (int mi = 0; mi < 4; mi++) {
    const int row0 = m0 + wm + mi * 16 + lq * 4;
    #pragma unroll
    for (int ni = 0; ni < 4; ni++) {
      const int col = n0 + wn + ni * 16 + l16;
      if (MODE == 1) {
        #pragma unroll
        for (int j = 0; j < 4; j++) {
          const size_t idx = ((size_t)bz * M + row0 + j) * N + col;
          ((float*)C)[idx] = acc[mi][ni][j] + bias[row0 + j];
        }
      } else {
        const int which = row0 >> 9;           // 0=q, 1=k, 2=v
        if (which < 2) {
          const int h = (row0 >> 6) & 7, d0 = row0 & 63;
          u16* dst = which ? kT : qT;
          us4 o;
          #pragma unroll
          for (int j = 0; j < 4; j++) o[j] = f2bf(acc[mi][ni][j]);
          *(us4*)&dst[((size_t)((bz * H_ + h) * N_) + col) * D_ + d0] = o;
        } else {
          // n-permute within 64-tile: n = kh*32+hi*16+lq2*4+j -> kh*32+lq2*8+hi*4+j
          const int cp = (col & ~63) | (col & 32) | (((col >> 2) & 3) << 3) |
                         (((col >> 4) & 1) << 2) | (col & 3);
          #pragma unroll
          for (int j = 0; j < 4; j++)
            vout[((size_t)(bz * 512) + (row0 & 511) + j) * N + cp] = f2bf(acc[mi][ni][j]);
        }
      }
    }
  }
}

// ---------------- flash attention v7: barrier-free, LDS-free ----------------
// block = (h, q-tile of 128, b*SPLIT+sp), 4 independent waves x 32 q-rows.
// K/V read directly from global (L1/L2-cached; K coalesced 2KB/wave-read,
// V pre-permuted so each PV b-frag is one b128). No barriers -> waves drift
// into different phases -> MFMA/VALU overlap across waves.
__global__ __launch_bounds__(256) void attn_kernel7(
    const u16* __restrict__ qT, const u16* __restrict__ kT,
    const u16* __restrict__ vp, float* __restrict__ po0,
    float* __restrict__ pl) {
  const int h = blockIdx.x;
  const int b = blockIdx.z >> 1, sp = blockIdx.z & 1;
  const int q0 = blockIdx.y * 128;
  const int tid = threadIdx.x;
  const int wave = tid >> 6, lane = tid & 63;
  const int l16 = lane & 15, lq = lane >> 4;
  const int kt0 = sp * NT;

  bf16x8 qf[2][2];
  {
    const u16* qb = qT + ((size_t)((b * H_ + h) * N_ + q0 + wave * 32)) * D_;
    #pragma unroll
    for (int qi = 0; qi < 2; qi++)
      #pragma unroll
      for (int dh = 0; dh < 2; dh++)
        qf[qi][dh] = *(const bf16x8*)(qb + (size_t)(qi * 16 + l16) * D_ + dh * 32 + lq * 8);
  }

  float l[2] = {0.f, 0.f};
  f32x4 acc[2][4];
  #pragma unroll
  for (int qi = 0; qi < 2; qi++)
    #pragma unroll
    for (int di = 0; di < 4; di++) {
      acc[qi][di][0] = 0.f; acc[qi][di][1] = 0.f; acc[qi][di][2] = 0.f; acc[qi][di][3] = 0.f;
    }
  const f32x4 z4 = {0.f, 0.f, 0.f, 0.f};

  // per-lane bases
  const u16* kb_ = kT + (size_t)(b * H_ + h) * N_ * D_ + (size_t)l16 * D_ + lq * 8;
  const u16* vb_ = vp + ((size_t)(b * 512) + h * D_ + l16) * N_ + lq * 8;

  #pragma unroll 1
  for (int t = 0; t < NT; t++) {
    const int kt = kt0 + t;
    #pragma unroll
    for (int kh = 0; kh < 2; kh++) {
      // ---- K frags (global, coalesced): rows kt*64 + kh*32 + nn*16 + l16 ----
      const u16* kp = kb_ + (size_t)(kt * 64 + kh * 32) * D_;
      const bf16x8 k0a = *(const bf16x8*)(kp);
      const bf16x8 k0b = *(const bf16x8*)(kp + 32);
      const bf16x8 k1a = *(const bf16x8*)(kp + 16 * D_);
      const bf16x8 k1b = *(const bf16x8*)(kp + 16 * D_ + 32);

      f32x4 s[2][2];
      __builtin_amdgcn_s_setprio(1);
      #pragma unroll
      for (int qi = 0; qi < 2; qi++) {
        s[qi][0] = __builtin_amdgcn_mfma_f32_16x16x32_bf16(k0a, qf[qi][0], z4, 0, 0, 0);
        s[qi][0] = __builtin_amdgcn_mfma_f32_16x16x32_bf16(k0b, qf[qi][1], s[qi][0], 0, 0, 0);
        s[qi][1] = __builtin_amdgcn_mfma_f32_16x16x32_bf16(k1a, qf[qi][0], z4, 0, 0, 0);
        s[qi][1] = __builtin_amdgcn_mfma_f32_16x16x32_bf16(k1b, qf[qi][1], s[qi][1], 0, 0, 0);
      }
      __builtin_amdgcn_s_setprio(0);

      // ---- p = exp2(s); l in-lane; pack into PV a-frag words ----
      union { u32 w[4]; bf16x8 v; } af[2];
      #pragma unroll
      for (int qi = 0; qi < 2; qi++) {
        float rs = 0.f;
        #pragma unroll
        for (int nn = 0; nn < 2; nn++) {
          const float p0 = __builtin_amdgcn_exp2f(s[qi][nn][0]);
          const float p1 = __builtin_amdgcn_exp2f(s[qi][nn][1]);
          const float p2 = __builtin_amdgcn_exp2f(s[qi][nn][2]);
          const float p3 = __builtin_amdgcn_exp2f(s[qi][nn][3]);
          rs += (p0 + p1) + (p2 + p3);
          af[qi].w[nn * 2]     = pack2bf(p0, p1);
          af[qi].w[nn * 2 + 1] = pack2bf(p2, p3);
        }
        l[qi] += rs;
      }

      // ---- PV: V b-frags direct from global (one b128 each) ----
      const u16* vq = vb_ + kt * 64 + kh * 32;
      __builtin_amdgcn_s_setprio(1);
      #pragma unroll
      for (int di = 0; di < 4; di++) {
        const bf16x8 vf = *(const bf16x8*)(vq + (size_t)(di * 16) * N_);
        #pragma unroll
        for (int qi = 0; qi < 2; qi++)
          acc[qi][di] = __builtin_amdgcn_mfma_f32_16x16x32_bf16(af[qi].v, vf, acc[qi][di], 0, 0, 0);
      }
      __builtin_amdgcn_s_setprio(0);
    }
  }

  // ---- epilogue: write unnormalized partial O (f32) + partial l ----
  float* po = po0 + (size_t)sp * (B_ * N_ * 512);
  #pragma unroll
  for (int qi = 0; qi < 2; qi++) {
    l[qi] += __shfl_xor(l[qi], 16);
    l[qi] += __shfl_xor(l[qi], 32);
  }
  if (lq == 0) {
    #pragma unroll
    for (int qi = 0; qi < 2; qi++) {
      const int n = q0 + wave * 32 + qi * 16 + l16;
      pl[((size_t)((sp * B_ + b) * H_) + h) * N_ + n] = l[qi];
    }
  }
  #pragma unroll
  for (int qi = 0; qi < 2; qi++)
    #pragma unroll
    for (int di = 0; di < 4; di++)
      #pragma unroll
      for (int j = 0; j < 4; j++) {
        const int n = q0 + wave * 32 + qi * 16 + lq * 4 + j;
        po[((size_t)(b * N_) + n) * 512 + h * D_ + di * 16 + l16] = acc[qi][di][j];
      }
}

// ---------------- combine: innerT = (po0+po1) * 1/(pl0+pl1), bf16 ----------------
__global__ __launch_bounds__(256) void combine_norm(
    const float* __restrict__ po0, const float* __restrict__ po1,
    const float* __restrict__ pl, u16* __restrict__ innerT) {
  const int bn = blockIdx.x * 4 + (threadIdx.x >> 6);   // b*N + n
  const int b = bn / N_, n = bn - b * N_;
  const int c0 = (threadIdx.x & 63) * 8;
  const int h = c0 >> 6;
  const size_t lidx = ((size_t)(b * H_) + h) * N_ + n;
  const float rl = 1.0f / (pl[lidx] + pl[lidx + (size_t)B_ * H_ * N_]);
  const size_t base = (size_t)bn * 512 + c0;
  const float4 a0 = *(const float4*)&po0[base];
  const float4 a1 = *(const float4*)&po0[base + 4];
  const float4 b0 = *(const float4*)&po1[base];
  const float4 b1 = *(const float4*)&po1[base + 4];
  us8 o;
  o[0] = f2bf((a0.x + b0.x) * rl); o[1] = f2bf((a0.y + b0.y) * rl);
  o[2] = f2bf((a0.z + b0.z) * rl); o[3] = f2bf((a0.w + b0.w) * rl);
  o[4] = f2bf((a1.x + b1.x) * rl); o[5] = f2bf((a1.y + b1.y) * rl);
  o[6] = f2bf((a1.z + b1.z) * rl); o[7] = f2bf((a1.w + b1.w) * rl);
  *(us8*)&innerT[base] = o;
}

extern "C" void kernel_launch(void* const* d_in, const int* in_sizes, int n_in,
                              void* d_out, int out_size, void* d_ws, size_t ws_size,
                              hipStream_t stream) {
  const float* x     = (const float*)d_in[0];
  const float* gamma = (const float*)d_in[1];
  const float* beta  = (const float*)d_in[2];
  const float* w_qkv = (const float*)d_in[3];
  const float* w_out = (const float*)d_in[4];
  const float* b_out = (const float*)d_in[5];
  float* out = (float*)d_out;

  char* ws = (char*)d_ws;
  float*  po0    = (float*)(ws + 0);
  float*  po1    = (float*)(ws + 18874368);
  u16*    vp     = (u16*)(ws + 37748736);
  u16*    qT     = (u16*)(ws + 47185920);
  u16*    kT     = (u16*)(ws + 56623104);
  float*  pl     = (float*)(ws + 66060288);
  float2* stats  = (float2*)(ws + 66650112);
  u16*    xnT    = (u16*)(ws + 0);          // aliases po0; dead after gemm1
  u16*    innerT = vp;                      // aliases vp; vp dead after attn

  gn_stats<<<dim3(B_ * G_), dim3(256), 0, stream>>>(x, stats);
  gn_apply_t<<<dim3(C_ / 64, N_ / 64, B_), dim3(256), 0, stream>>>(x, stats, gamma, beta, xnT);
  gemm_bf16<2><<<dim3(12, 18, B_), dim3(256), 0, stream>>>(
      w_qkv, xnT, nullptr, nullptr, qT, kT, vp, 1536, N_, C_);
  attn_kernel7<<<dim3(H_, N_ / 128, B_ * SPLIT), dim3(256), 0, stream>>>(qT, kT, vp, po0, pl);
  combine_norm<<<dim3(B_ * N_ / 4), dim3(256), 0, stream>>>(po0, po1, pl, innerT);
  gemm_bf16<1><<<dim3(4, 18, B_), dim3(256), 0, stream>>>(
      w_out, innerT, (void*)out, b_out, nullptr, nullptr, nullptr, C_, N_, C_);
}